// Round 11
// baseline (250.484 us; speedup 1.0000x reference)
//
#include <hip/hip_runtime.h>
#include <hip/hip_bf16.h>

#define HW 3136

typedef short s16x8 __attribute__((ext_vector_type(8)));
typedef float f32x4 __attribute__((ext_vector_type(4)));
typedef unsigned short us4 __attribute__((ext_vector_type(4)));
typedef unsigned short us8 __attribute__((ext_vector_type(8)));

__device__ inline unsigned short f2bf(float f) {
  union { float f; unsigned int u; } v; v.f = f;
  unsigned int r = v.u + 0x7fff + ((v.u >> 16) & 1);
  return (unsigned short)(r >> 16);
}
__device__ inline float bf2f(unsigned short b) {
  union { unsigned int u; float f; } v; v.u = (unsigned int)b << 16;
  return v.f;
}

// ---------------------------------------------------------------------------
// Weight prep. y=0..2: q_w/k_w/v_w -> plain bf16. y=3: o_w -> hi/lo bf16 pair.
// ---------------------------------------------------------------------------
__global__ __launch_bounds__(256) void wconv_kernel(
    const float* __restrict__ w0, const float* __restrict__ w1,
    const float* __restrict__ w2, const float* __restrict__ w3,
    unsigned short* __restrict__ o0, unsigned short* __restrict__ o1,
    unsigned short* __restrict__ o2, unsigned short* __restrict__ o3h,
    unsigned short* __restrict__ o3l) {
  int i = blockIdx.x * 256 + threadIdx.x;
  int y = blockIdx.y;
  if (y < 3) {
    const float* s = (y == 0) ? w0 : (y == 1) ? w1 : w2;
    unsigned short* d = (y == 0) ? o0 : (y == 1) ? o1 : o2;
    d[i] = f2bf(s[i]);
  } else {
    float x = w3[i];
    unsigned short hi = f2bf(x);
    o3h[i] = hi;
    o3l[i] = f2bf(x - bf2f(hi));
  }
}

// ---------------------------------------------------------------------------
// Transpose x: f32 [b][128][HW] -> bf16 [b][p][128]. grid (49, 4), block 256.
// ---------------------------------------------------------------------------
__global__ __launch_bounds__(256) void xpose_kernel(
    const float* __restrict__ x, unsigned short* __restrict__ xT) {
  int b = blockIdx.y;
  int t = threadIdx.x;
  int p = blockIdx.x * 64 + (t & 63);
  int cq = t >> 6;
  const float* src = x + ((size_t)b * 128 + cq * 32) * HW + p;
  unsigned short tmp[32];
  #pragma unroll
  for (int j = 0; j < 32; ++j) tmp[j] = f2bf(src[(size_t)j * HW]);
  unsigned short* dst = xT + ((size_t)b * HW + p) * 128 + cq * 32;
  #pragma unroll
  for (int k = 0; k < 4; ++k) *(us8*)&dst[k * 8] = *(us8*)&tmp[k * 8];
}

// ---------------------------------------------------------------------------
// MFMA projection GEMM (q only now). MODE 2: f32 [c][p] + bf16 [p][o]*scale.
// grid (98, 8), block 128.
// ---------------------------------------------------------------------------
template <int MODE>
__global__ __launch_bounds__(128) void gemm_mfma_kernel(
    const unsigned short* __restrict__ InT, const unsigned short* __restrict__ Wbf,
    const float* __restrict__ bias, float* __restrict__ Outf,
    unsigned short* __restrict__ Outb) {
  int by = blockIdx.y;
  int b = by >> 1, oh = by & 1;
  int t = threadIdx.x;
  int w = t >> 6, l = t & 63;
  int lq = l & 15, h = l >> 4;
  int p = blockIdx.x * 32 + w * 16 + lq;

  s16x8 bfr[4];
  const unsigned short* bsrc = InT + ((size_t)b * HW + p) * 128 + h * 8;
  #pragma unroll
  for (int k = 0; k < 4; ++k) bfr[k] = *(const s16x8*)&bsrc[k * 32];

  f32x4 acc[4] = {};
  #pragma unroll
  for (int k = 0; k < 4; ++k) {
    #pragma unroll
    for (int ot = 0; ot < 4; ++ot) {
      int og = oh * 4 + ot;
      s16x8 af = *(const s16x8*)&Wbf[(size_t)(og * 16 + lq) * 128 + k * 32 + h * 8];
      acc[ot] = __builtin_amdgcn_mfma_f32_16x16x32_bf16(af, bfr[k], acc[ot], 0, 0, 0);
    }
  }

  size_t cb = (size_t)b * 128 * HW;
  #pragma unroll
  for (int ot = 0; ot < 4; ++ot) {
    int og = oh * 4 + ot;
    float4 bv = *(const float4*)&bias[og * 16 + h * 4];
    float r[4] = {acc[ot][0] + bv.x, acc[ot][1] + bv.y,
                  acc[ot][2] + bv.z, acc[ot][3] + bv.w};
    if (MODE == 2) {
      #pragma unroll
      for (int i = 0; i < 4; ++i)
        Outf[cb + (size_t)(og * 16 + h * 4 + i) * HW + p] = r[i];
    }
    if (MODE == 1) {
      #pragma unroll
      for (int i = 0; i < 4; ++i)
        Outb[cb + (size_t)(og * 16 + h * 4 + i) * HW + p] = f2bf(r[i]);
    }
    if (MODE >= 2) {
      const float S = (MODE == 2) ? 0.25503968151135f : 1.0f;  // rsqrt(32)*log2e
      us4 rb;
      #pragma unroll
      for (int i = 0; i < 4; ++i) rb[i] = f2bf(r[i] * S);
      *(us4*)&Outb[((size_t)b * HW + p) * 128 + og * 16 + h * 4] = rb;
    }
  }
}

// ---------------------------------------------------------------------------
// Fused K+V projection: input fragments loaded ONCE, two weight sets, two
// epilogues (K -> bf16 [p][o]; V -> bf16 [c][p]). grid (98, 8), block 128.
// ---------------------------------------------------------------------------
__global__ __launch_bounds__(128) void gemm_kv_kernel(
    const unsigned short* __restrict__ InT, const unsigned short* __restrict__ Wk,
    const unsigned short* __restrict__ Wv, const float* __restrict__ k_b,
    const float* __restrict__ v_b, unsigned short* __restrict__ kbT,
    unsigned short* __restrict__ vb) {
  int by = blockIdx.y;
  int b = by >> 1, oh = by & 1;
  int t = threadIdx.x;
  int w = t >> 6, l = t & 63;
  int lq = l & 15, h = l >> 4;
  int p = blockIdx.x * 32 + w * 16 + lq;

  s16x8 bfr[4];
  const unsigned short* bsrc = InT + ((size_t)b * HW + p) * 128 + h * 8;
  #pragma unroll
  for (int k = 0; k < 4; ++k) bfr[k] = *(const s16x8*)&bsrc[k * 32];

  // ---- K ----
  {
    f32x4 acc[4] = {};
    #pragma unroll
    for (int k = 0; k < 4; ++k) {
      #pragma unroll
      for (int ot = 0; ot < 4; ++ot) {
        int og = oh * 4 + ot;
        s16x8 af = *(const s16x8*)&Wk[(size_t)(og * 16 + lq) * 128 + k * 32 + h * 8];
        acc[ot] = __builtin_amdgcn_mfma_f32_16x16x32_bf16(af, bfr[k], acc[ot], 0, 0, 0);
      }
    }
    #pragma unroll
    for (int ot = 0; ot < 4; ++ot) {
      int og = oh * 4 + ot;
      float4 bv = *(const float4*)&k_b[og * 16 + h * 4];
      us4 rb;
      #pragma unroll
      for (int i = 0; i < 4; ++i) rb[i] = f2bf(acc[ot][i] + bv[i]);
      *(us4*)&kbT[((size_t)b * HW + p) * 128 + og * 16 + h * 4] = rb;
    }
  }
  // ---- V ----
  {
    f32x4 acc[4] = {};
    #pragma unroll
    for (int k = 0; k < 4; ++k) {
      #pragma unroll
      for (int ot = 0; ot < 4; ++ot) {
        int og = oh * 4 + ot;
        s16x8 af = *(const s16x8*)&Wv[(size_t)(og * 16 + lq) * 128 + k * 32 + h * 8];
        acc[ot] = __builtin_amdgcn_mfma_f32_16x16x32_bf16(af, bfr[k], acc[ot], 0, 0, 0);
      }
    }
    size_t cb = (size_t)b * 128 * HW;
    #pragma unroll
    for (int ot = 0; ot < 4; ++ot) {
      int og = oh * 4 + ot;
      float4 bv = *(const float4*)&v_b[og * 16 + h * 4];
      #pragma unroll
      for (int i = 0; i < 4; ++i)
        vb[cb + (size_t)(og * 16 + h * 4 + i) * HW + p] = f2bf(acc[ot][i] + bv[i]);
    }
  }
}

// ---------------------------------------------------------------------------
// o-projection MFMA hi/lo (unchanged).
// ---------------------------------------------------------------------------
__global__ __launch_bounds__(128) void o_gemm_kernel(
    const unsigned short* __restrict__ AHi, const unsigned short* __restrict__ ALo,
    const unsigned short* __restrict__ WHi, const unsigned short* __restrict__ WLo,
    const float* __restrict__ bias, float* __restrict__ Outf) {
  int by = blockIdx.y;
  int b = by >> 1, oh = by & 1;
  int t = threadIdx.x;
  int w = t >> 6, l = t & 63;
  int lq = l & 15, h = l >> 4;
  int p = blockIdx.x * 32 + w * 16 + lq;

  s16x8 bH[4], bL[4];
  const unsigned short* bsH = AHi + ((size_t)b * HW + p) * 128 + h * 8;
  const unsigned short* bsL = ALo + ((size_t)b * HW + p) * 128 + h * 8;
  #pragma unroll
  for (int k = 0; k < 4; ++k) {
    bH[k] = *(const s16x8*)&bsH[k * 32];
    bL[k] = *(const s16x8*)&bsL[k * 32];
  }

  f32x4 acc[4] = {};
  #pragma unroll
  for (int k = 0; k < 4; ++k) {
    #pragma unroll
    for (int ot = 0; ot < 4; ++ot) {
      int og = oh * 4 + ot;
      size_t wi = (size_t)(og * 16 + lq) * 128 + k * 32 + h * 8;
      s16x8 aH = *(const s16x8*)&WHi[wi];
      s16x8 aL = *(const s16x8*)&WLo[wi];
      acc[ot] = __builtin_amdgcn_mfma_f32_16x16x32_bf16(aH, bH[k], acc[ot], 0, 0, 0);
      acc[ot] = __builtin_amdgcn_mfma_f32_16x16x32_bf16(aH, bL[k], acc[ot], 0, 0, 0);
      acc[ot] = __builtin_amdgcn_mfma_f32_16x16x32_bf16(aL, bH[k], acc[ot], 0, 0, 0);
    }
  }

  size_t cb = (size_t)b * 128 * HW;
  #pragma unroll
  for (int ot = 0; ot < 4; ++ot) {
    int og = oh * 4 + ot;
    float4 bv = *(const float4*)&bias[og * 16 + h * 4];
    #pragma unroll
    for (int i = 0; i < 4; ++i)
      Outf[cb + (size_t)(og * 16 + h * 4 + i) * HW + p] = acc[ot][i] + bv[i];
  }
}

// ---------------------------------------------------------------------------
// Offset branch (unchanged).
// ---------------------------------------------------------------------------
__global__ __launch_bounds__(256) void offset_kernel(
    const float* __restrict__ q, const float* __restrict__ dw_w,
    const float* __restrict__ dw_b, const float* __restrict__ ln_g,
    const float* __restrict__ ln_b, const float* __restrict__ off_w,
    float* __restrict__ pos) {
  __shared__ float vs[64][65];
  __shared__ float mu_s[64], rs_s[64];
  __shared__ float part[4][64][2];
  int bg = blockIdx.x, h = blockIdx.y;
  int t = threadIdx.x;
  int w = t & 63;
  int cq = t >> 6;
  int b = bg >> 1, g = bg & 1;
  const float* qb = q + ((size_t)b * 128 + (size_t)g * 64) * HW;

  #pragma unroll
  for (int i = 0; i < 16; ++i) {
    int c = cq * 16 + i;
    float acc = dw_b[c];
    const float* qc = qb + (size_t)c * HW;
    const float* wc = dw_w + c * 49;
    #pragma unroll
    for (int ky = 0; ky < 7; ++ky) {
      int y = h + ky - 3;
      if (y >= 0 && y < 56) {
        #pragma unroll
        for (int kx = 0; kx < 7; ++kx) {
          int xx = w + kx - 3;
          if (xx >= 0 && xx < 56)
            acc += qc[y * 56 + xx] * wc[ky * 7 + kx];
        }
      }
    }
    vs[c][w] = acc;
  }
  __syncthreads();

  if (cq == 0) {
    float sum = 0.f;
    #pragma unroll 8
    for (int c = 0; c < 64; ++c) sum += vs[c][w];
    float mu = sum * 0.015625f;
    float var = 0.f;
    #pragma unroll 8
    for (int c = 0; c < 64; ++c) { float d = vs[c][w] - mu; var += d * d; }
    mu_s[w] = mu;
    rs_s[w] = rsqrtf(var * 0.015625f + 1e-5f);
  }
  __syncthreads();

  {
    float mu = mu_s[w], rstd = rs_s[w];
    float oy = 0.f, ox = 0.f;
    #pragma unroll
    for (int i = 0; i < 16; ++i) {
      int c = cq * 16 + i;
      float hn = (vs[c][w] - mu) * rstd * ln_g[c] + ln_b[c];
      hn = 0.5f * hn * (1.f + erff(hn * 0.70710678118654752f));
      oy += off_w[c] * hn;
      ox += off_w[64 + c] * hn;
    }
    part[cq][w][0] = oy;
    part[cq][w][1] = ox;
  }
  __syncthreads();

  if (cq == 0 && w < 56) {
    float oy = part[0][w][0] + part[1][w][0] + part[2][w][0] + part[3][w][0];
    float ox = part[0][w][1] + part[1][w][1] + part[2][w][1] + part[3][w][1];
    float py = tanhf(oy) * (2.0f / 56.f) + ((h + 0.5f) * (2.f / 56.f) - 1.f);
    float px = tanhf(ox) * (2.0f / 56.f) + ((w + 0.5f) * (2.f / 56.f) - 1.f);
    int idx = bg * HW + h * 56 + w;
    pos[idx * 2 + 0] = (px + 1.f) * 0.5f * 55.f;
    pos[idx * 2 + 1] = (py + 1.f) * 0.5f * 55.f;
  }
}

// ---------------------------------------------------------------------------
// Bilinear grid sample -> bf16 [b][p][128] (unchanged).
// ---------------------------------------------------------------------------
__global__ __launch_bounds__(256) void sample_kernel(
    const float* __restrict__ x, const float* __restrict__ pos,
    unsigned short* __restrict__ xsT) {
  int t = threadIdx.x;
  int p = blockIdx.x * 64 + (t & 63);
  int cg = t >> 6;
  int bg = p / HW, pp = p % HW;
  int b = bg >> 1, g = bg & 1;
  float gx = pos[2 * p], gy = pos[2 * p + 1];
  float x0f = floorf(gx), y0f = floorf(gy);
  float wx1 = gx - x0f, wx0 = 1.f - wx1;
  float wy1 = gy - y0f, wy0 = 1.f - wy1;
  int x0 = (int)x0f, y0 = (int)y0f;
  int x1 = x0 + 1, y1 = y0 + 1;
  float vx0 = (x0 >= 0 && x0 < 56) ? 1.f : 0.f;
  float vx1 = (x1 >= 0 && x1 < 56) ? 1.f : 0.f;
  float vy0 = (y0 >= 0 && y0 < 56) ? 1.f : 0.f;
  float vy1 = (y1 >= 0 && y1 < 56) ? 1.f : 0.f;
  int xc0 = min(max(x0, 0), 55), xc1 = min(max(x1, 0), 55);
  int yc0 = min(max(y0, 0), 55), yc1 = min(max(y1, 0), 55);
  float w00 = wx0 * wy0 * vx0 * vy0, w10 = wx1 * wy0 * vx1 * vy0;
  float w01 = wx0 * wy1 * vx0 * vy1, w11 = wx1 * wy1 * vx1 * vy1;
  int i00 = yc0 * 56 + xc0, i10 = yc0 * 56 + xc1;
  int i01 = yc1 * 56 + xc0, i11 = yc1 * 56 + xc1;
  const float* xb = x + ((size_t)b * 128 + (size_t)g * 64 + cg * 16) * HW;
  unsigned short tmp[16];
  #pragma unroll 4
  for (int i = 0; i < 16; ++i) {
    const float* xc = xb + (size_t)i * HW;
    tmp[i] = f2bf(w00 * xc[i00] + w10 * xc[i10] + w01 * xc[i01] + w11 * xc[i11]);
  }
  unsigned short* dst = xsT + ((size_t)b * HW + pp) * 128 + g * 64 + cg * 16;
  *(us8*)&dst[0] = *(us8*)&tmp[0];
  *(us8*)&dst[8] = *(us8*)&tmp[8];
}

// ---------------------------------------------------------------------------
// MFMA flash attention v11: ONE WAVE PER BLOCK, ZERO barriers.
// Each wave owns 16 q rows and the whole K loop; K double-buffer is
// wave-private LDS (intra-wave DS ordering makes write->read safe without
// sync), V prefetched to regs one tile ahead, K two ahead. Independent
// waves drift out of phase, so a SIMD's ~3 resident waves time-share the
// MFMA/trans/LDS pipes instead of convoying on a barrier.
// grid (196, 16), block 64. Output hi/lo bf16 [b][p][128].
// ---------------------------------------------------------------------------
__global__ __launch_bounds__(64) void attn_mfma_kernel(
    const unsigned short* __restrict__ qT, const unsigned short* __restrict__ kT,
    const unsigned short* __restrict__ vbf, unsigned short* __restrict__ aoHi,
    unsigned short* __restrict__ aoLo) {
  __shared__ __align__(16) unsigned short Klds[2][64][40];
  __shared__ __align__(16) unsigned short Plds[16][68];
  int bh = blockIdx.y;
  int b = bh >> 2, hd = bh & 3;
  int l = threadIdx.x;          // 0..63 (one wave)
  int lq = l & 15, h = l >> 4;
  int q0 = blockIdx.x * 16;
  size_t vbase = (size_t)bh * 32 * HW;

  union S8 { s16x8 v; long long q[2]; unsigned short u[8]; };

  S8 qf;
  qf.v = *(const s16x8*)&qT[((size_t)b * HW + q0 + lq) * 128 + hd * 32 + h * 8];

  // K staging: 4 sub-loads/tile; sub i covers row i*16 + (l>>2), seg l&3
  int srow = l >> 2, sseg = l & 3;
  const unsigned short* ksrc =
      kT + ((size_t)b * HW + srow) * 128 + hd * 32 + sseg * 8;
  unsigned short* kdst = &Klds[0][srow][sseg * 8];

  const unsigned short* vl = vbf + vbase + (size_t)lq * HW + h * 8;

  f32x4 oacc[2] = {{0.f, 0.f, 0.f, 0.f}, {0.f, 0.f, 0.f, 0.f}};
  float lsum = 0.f;

  // ---- prologue: stage K(0), issue K(1), prefetch V(0) ----
  S8 kreg[4], vreg[4];
  #pragma unroll
  for (int i = 0; i < 4; ++i)
    kreg[i].v = *(const s16x8*)&ksrc[(size_t)(i * 16) * 128];
  #pragma unroll
  for (int i = 0; i < 4; ++i)
    *(s16x8*)(kdst + i * 16 * 40) = kreg[i].v;
  #pragma unroll
  for (int i = 0; i < 4; ++i)
    kreg[i].v = *(const s16x8*)&ksrc[(size_t)(64 + i * 16) * 128];
  #pragma unroll
  for (int c = 0; c < 2; ++c)
    #pragma unroll
    for (int n = 0; n < 2; ++n)
      vreg[c * 2 + n].v = *(const s16x8*)&vl[(size_t)(n * 16) * HW + c * 32];

  for (int tix = 0; tix < 49; ++tix) {
    int cur = tix & 1;
    int kbV = (tix + 1 < 49) ? (tix + 1) * 64 : 0;
    int kbK = (tix + 2 < 49) ? (tix + 2) * 64 : 3072;  // clamp to tile 48

    // ---- QK: 4 MFMAs from Klds[cur] (wave-private, no barrier) ----
    f32x4 st[4];
    #pragma unroll
    for (int tt = 0; tt < 4; ++tt) {
      S8 af;
      af.v = *(const s16x8*)&Klds[cur][tt * 16 + lq][h * 8];
      st[tt] = __builtin_amdgcn_mfma_f32_16x16x32_bf16(
          af.v, qf.v, (f32x4){0.f, 0.f, 0.f, 0.f}, 0, 0, 0);
    }

    // ---- write K(t+1) to the other buffer; issue K(t+2) loads ----
    #pragma unroll
    for (int i = 0; i < 4; ++i)
      *(s16x8*)(kdst + (cur ^ 1) * (64 * 40) + i * 16 * 40) = kreg[i].v;
    #pragma unroll
    for (int i = 0; i < 4; ++i)
      kreg[i].v = *(const s16x8*)&ksrc[(size_t)(kbK + i * 16) * 128];

    // ---- softmax numerator (exp2 domain, raw v_exp, no max) ----
    #pragma unroll
    for (int tt = 0; tt < 4; ++tt) {
      float p0, p1, p2, p3;
      asm("v_exp_f32 %0, %1" : "=v"(p0) : "v"(st[tt][0]));
      asm("v_exp_f32 %0, %1" : "=v"(p1) : "v"(st[tt][1]));
      asm("v_exp_f32 %0, %1" : "=v"(p2) : "v"(st[tt][2]));
      asm("v_exp_f32 %0, %1" : "=v"(p3) : "v"(st[tt][3]));
      lsum += (p0 + p1) + (p2 + p3);
      unsigned int lo, hi;
      asm("v_cvt_pk_bf16_f32 %0, %1, %2" : "=v"(lo) : "v"(p0), "v"(p1));
      asm("v_cvt_pk_bf16_f32 %0, %1, %2" : "=v"(hi) : "v"(p2), "v"(p3));
      unsigned long long pk = (unsigned long long)lo | ((unsigned long long)hi << 32);
      *(unsigned long long*)&Plds[lq][tt * 16 + h * 4] = pk;
    }

    // ---- PV: 4 MFMAs, V in registers; P bounce same-wave (in-order DS) ----
    #pragma unroll
    for (int c = 0; c < 2; ++c) {
      S8 pf;
      pf.q[0] = *(const long long*)&Plds[lq][c * 32 + h * 8];
      pf.q[1] = *(const long long*)&Plds[lq][c * 32 + h * 8 + 4];
      #pragma unroll
      for (int n = 0; n < 2; ++n)
        oacc[n] = __builtin_amdgcn_mfma_f32_16x16x32_bf16(
            vreg[c * 2 + n].v, pf.v, oacc[n], 0, 0, 0);
    }

    // ---- prefetch V(t+1) ----
    #pragma unroll
    for (int c = 0; c < 2; ++c)
      #pragma unroll
      for (int n = 0; n < 2; ++n)
        vreg[c * 2 + n].v =
            *(const s16x8*)&vl[(size_t)(n * 16) * HW + kbV + c * 32];
  }

  lsum += __shfl_xor(lsum, 16);
  lsum += __shfl_xor(lsum, 32);
  float inv = 1.f / lsum;
  size_t obase = ((size_t)b * HW + q0 + lq) * 128 + hd * 32;
  #pragma unroll
  for (int n = 0; n < 2; ++n) {
    us4 rh, rl;
    #pragma unroll
    for (int r = 0; r < 4; ++r) {
      float v = oacc[n][r] * inv;
      unsigned short hi = f2bf(v);
      rh[r] = hi;
      rl[r] = f2bf(v - bf2f(hi));
    }
    *(us4*)&aoHi[obase + n * 16 + h * 4] = rh;
    *(us4*)&aoLo[obase + n * 16 + h * 4] = rl;
  }
}

// ---------------------------------------------------------------------------
extern "C" void kernel_launch(void* const* d_in, const int* in_sizes, int n_in,
                              void* d_out, int out_size, void* d_ws, size_t ws_size,
                              hipStream_t stream) {
  const float* x    = (const float*)d_in[0];
  const float* dw_w = (const float*)d_in[1];
  const float* dw_b = (const float*)d_in[2];
  const float* ln_g = (const float*)d_in[3];
  const float* ln_b = (const float*)d_in[4];
  const float* offw = (const float*)d_in[5];
  const float* q_w  = (const float*)d_in[6];
  const float* q_b  = (const float*)d_in[7];
  const float* k_w  = (const float*)d_in[8];
  const float* k_b  = (const float*)d_in[9];
  const float* v_w  = (const float*)d_in[10];
  const float* v_b  = (const float*)d_in[11];
  const float* o_w  = (const float*)d_in[12];
  const float* o_b  = (const float*)d_in[13];

  const size_t NE = 1605632;  // 4*128*3136
  float* ws  = (float*)d_ws;
  float* q   = ws;                   // fp32 q [c][p] (offset branch)
  float* pos = q + NE;               // 50176 floats
  unsigned short* xT   = (unsigned short*)(pos + 50176);  // x bf16 [p][128]
  unsigned short* xsT  = xT + NE;    // sampled bf16 [p][128]
  unsigned short* qbT  = xsT + NE;   // q bf16 [p][128] scaled
  unsigned short* kbT  = qbT + NE;   // k bf16 [p][128]
  unsigned short* vb   = kbT + NE;   // v bf16 [c][p]
  unsigned short* aoHi = vb + NE;    // attn out hi bf16 [p][128]
  unsigned short* aoLo = aoHi + NE;  // attn out lo bf16 [p][128]
  unsigned short* Wq   = aoLo + NE;  // 16384 each
  unsigned short* Wk   = Wq + 16384;
  unsigned short* Wv   = Wk + 16384;
  unsigned short* WoH  = Wv + 16384;
  unsigned short* WoL  = WoH + 16384;
  float* out = (float*)d_out;

  wconv_kernel<<<dim3(64, 4), 256, 0, stream>>>(q_w, k_w, v_w, o_w,
                                                Wq, Wk, Wv, WoH, WoL);
  xpose_kernel<<<dim3(49, 4), 256, 0, stream>>>(x, xT);
  gemm_mfma_kernel<2><<<dim3(98, 8), 128, 0, stream>>>(xT, Wq, q_b, q, qbT);
  offset_kernel<<<dim3(8, 56), 256, 0, stream>>>(q, dw_w, dw_b, ln_g, ln_b, offw, pos);
  sample_kernel<<<dim3(392), 256, 0, stream>>>(x, pos, xsT);
  gemm_kv_kernel<<<dim3(98, 8), 128, 0, stream>>>(xsT, Wk, Wv, k_b, v_b, kbT, vb);
  attn_mfma_kernel<<<dim3(196, 16), 64, 0, stream>>>(qbT, kbT, vb, aoHi, aoLo);
  o_gemm_kernel<<<dim3(98, 8), 128, 0, stream>>>(aoHi, aoLo, WoH, WoL, o_b, out);
}

// Round 12
// 242.481 us; speedup vs baseline: 1.0330x; 1.0330x over previous
//
#include <hip/hip_runtime.h>
#include <hip/hip_bf16.h>

#define HW 3136

typedef short s16x8 __attribute__((ext_vector_type(8)));
typedef float f32x4 __attribute__((ext_vector_type(4)));
typedef unsigned short us4 __attribute__((ext_vector_type(4)));
typedef unsigned short us8 __attribute__((ext_vector_type(8)));

__device__ inline unsigned short f2bf(float f) {
  union { float f; unsigned int u; } v; v.f = f;
  unsigned int r = v.u + 0x7fff + ((v.u >> 16) & 1);
  return (unsigned short)(r >> 16);
}
__device__ inline float bf2f(unsigned short b) {
  union { unsigned int u; float f; } v; v.u = (unsigned int)b << 16;
  return v.f;
}

// ---------------------------------------------------------------------------
// Weight prep. y=0..2: q_w/k_w/v_w -> plain bf16. y=3: o_w -> hi/lo bf16 pair.
// ---------------------------------------------------------------------------
__global__ __launch_bounds__(256) void wconv_kernel(
    const float* __restrict__ w0, const float* __restrict__ w1,
    const float* __restrict__ w2, const float* __restrict__ w3,
    unsigned short* __restrict__ o0, unsigned short* __restrict__ o1,
    unsigned short* __restrict__ o2, unsigned short* __restrict__ o3h,
    unsigned short* __restrict__ o3l) {
  int i = blockIdx.x * 256 + threadIdx.x;
  int y = blockIdx.y;
  if (y < 3) {
    const float* s = (y == 0) ? w0 : (y == 1) ? w1 : w2;
    unsigned short* d = (y == 0) ? o0 : (y == 1) ? o1 : o2;
    d[i] = f2bf(s[i]);
  } else {
    float x = w3[i];
    unsigned short hi = f2bf(x);
    o3h[i] = hi;
    o3l[i] = f2bf(x - bf2f(hi));
  }
}

// ---------------------------------------------------------------------------
// q-projection MFMA with FUSED transpose: reads x f32 [c][p] directly,
// converts fragments to bf16 in-register (identical numerics to the old
// xpose->gemm path). Writes q f32 [c][p] (offset branch) + qbT bf16 [p][o]
// scaled by rsqrt(32)*log2e. grid (98, 8), block 128.
// ---------------------------------------------------------------------------
__global__ __launch_bounds__(128) void gemm_q_kernel(
    const float* __restrict__ x, const unsigned short* __restrict__ Wq,
    const float* __restrict__ bias, float* __restrict__ Outf,
    unsigned short* __restrict__ Outb) {
  int by = blockIdx.y;
  int b = by >> 1, oh = by & 1;
  int t = threadIdx.x;
  int w = t >> 6, l = t & 63;
  int lq = l & 15, h = l >> 4;
  int p = blockIdx.x * 32 + w * 16 + lq;

  union S8 { s16x8 v; unsigned short u[8]; };
  S8 bfr[4];
  const float* xs = x + (size_t)b * 128 * HW + p;
  #pragma unroll
  for (int k = 0; k < 4; ++k)
    #pragma unroll
    for (int j = 0; j < 8; ++j)
      bfr[k].u[j] = f2bf(xs[(size_t)(k * 32 + h * 8 + j) * HW]);

  f32x4 acc[4] = {};
  #pragma unroll
  for (int k = 0; k < 4; ++k) {
    #pragma unroll
    for (int ot = 0; ot < 4; ++ot) {
      int og = oh * 4 + ot;
      s16x8 af = *(const s16x8*)&Wq[(size_t)(og * 16 + lq) * 128 + k * 32 + h * 8];
      acc[ot] = __builtin_amdgcn_mfma_f32_16x16x32_bf16(af, bfr[k].v, acc[ot], 0, 0, 0);
    }
  }

  size_t cb = (size_t)b * 128 * HW;
  #pragma unroll
  for (int ot = 0; ot < 4; ++ot) {
    int og = oh * 4 + ot;
    float4 bv = *(const float4*)&bias[og * 16 + h * 4];
    float r[4] = {acc[ot][0] + bv.x, acc[ot][1] + bv.y,
                  acc[ot][2] + bv.z, acc[ot][3] + bv.w};
    #pragma unroll
    for (int i = 0; i < 4; ++i)
      Outf[cb + (size_t)(og * 16 + h * 4 + i) * HW + p] = r[i];
    const float S = 0.25503968151135f;  // rsqrt(32)*log2e
    us4 rb;
    #pragma unroll
    for (int i = 0; i < 4; ++i) rb[i] = f2bf(r[i] * S);
    *(us4*)&Outb[((size_t)b * HW + p) * 128 + og * 16 + h * 4] = rb;
  }
}

// ---------------------------------------------------------------------------
// Fused K+V projection (unchanged from round 11). grid (98, 8), block 128.
// ---------------------------------------------------------------------------
__global__ __launch_bounds__(128) void gemm_kv_kernel(
    const unsigned short* __restrict__ InT, const unsigned short* __restrict__ Wk,
    const unsigned short* __restrict__ Wv, const float* __restrict__ k_b,
    const float* __restrict__ v_b, unsigned short* __restrict__ kbT,
    unsigned short* __restrict__ vb) {
  int by = blockIdx.y;
  int b = by >> 1, oh = by & 1;
  int t = threadIdx.x;
  int w = t >> 6, l = t & 63;
  int lq = l & 15, h = l >> 4;
  int p = blockIdx.x * 32 + w * 16 + lq;

  s16x8 bfr[4];
  const unsigned short* bsrc = InT + ((size_t)b * HW + p) * 128 + h * 8;
  #pragma unroll
  for (int k = 0; k < 4; ++k) bfr[k] = *(const s16x8*)&bsrc[k * 32];

  {
    f32x4 acc[4] = {};
    #pragma unroll
    for (int k = 0; k < 4; ++k) {
      #pragma unroll
      for (int ot = 0; ot < 4; ++ot) {
        int og = oh * 4 + ot;
        s16x8 af = *(const s16x8*)&Wk[(size_t)(og * 16 + lq) * 128 + k * 32 + h * 8];
        acc[ot] = __builtin_amdgcn_mfma_f32_16x16x32_bf16(af, bfr[k], acc[ot], 0, 0, 0);
      }
    }
    #pragma unroll
    for (int ot = 0; ot < 4; ++ot) {
      int og = oh * 4 + ot;
      float4 bv = *(const float4*)&k_b[og * 16 + h * 4];
      us4 rb;
      #pragma unroll
      for (int i = 0; i < 4; ++i) rb[i] = f2bf(acc[ot][i] + bv[i]);
      *(us4*)&kbT[((size_t)b * HW + p) * 128 + og * 16 + h * 4] = rb;
    }
  }
  {
    f32x4 acc[4] = {};
    #pragma unroll
    for (int k = 0; k < 4; ++k) {
      #pragma unroll
      for (int ot = 0; ot < 4; ++ot) {
        int og = oh * 4 + ot;
        s16x8 af = *(const s16x8*)&Wv[(size_t)(og * 16 + lq) * 128 + k * 32 + h * 8];
        acc[ot] = __builtin_amdgcn_mfma_f32_16x16x32_bf16(af, bfr[k], acc[ot], 0, 0, 0);
      }
    }
    size_t cb = (size_t)b * 128 * HW;
    #pragma unroll
    for (int ot = 0; ot < 4; ++ot) {
      int og = oh * 4 + ot;
      float4 bv = *(const float4*)&v_b[og * 16 + h * 4];
      #pragma unroll
      for (int i = 0; i < 4; ++i)
        vb[cb + (size_t)(og * 16 + h * 4 + i) * HW + p] = f2bf(acc[ot][i] + bv[i]);
    }
  }
}

// ---------------------------------------------------------------------------
// o-projection MFMA hi/lo (unchanged).
// ---------------------------------------------------------------------------
__global__ __launch_bounds__(128) void o_gemm_kernel(
    const unsigned short* __restrict__ AHi, const unsigned short* __restrict__ ALo,
    const unsigned short* __restrict__ WHi, const unsigned short* __restrict__ WLo,
    const float* __restrict__ bias, float* __restrict__ Outf) {
  int by = blockIdx.y;
  int b = by >> 1, oh = by & 1;
  int t = threadIdx.x;
  int w = t >> 6, l = t & 63;
  int lq = l & 15, h = l >> 4;
  int p = blockIdx.x * 32 + w * 16 + lq;

  s16x8 bH[4], bL[4];
  const unsigned short* bsH = AHi + ((size_t)b * HW + p) * 128 + h * 8;
  const unsigned short* bsL = ALo + ((size_t)b * HW + p) * 128 + h * 8;
  #pragma unroll
  for (int k = 0; k < 4; ++k) {
    bH[k] = *(const s16x8*)&bsH[k * 32];
    bL[k] = *(const s16x8*)&bsL[k * 32];
  }

  f32x4 acc[4] = {};
  #pragma unroll
  for (int k = 0; k < 4; ++k) {
    #pragma unroll
    for (int ot = 0; ot < 4; ++ot) {
      int og = oh * 4 + ot;
      size_t wi = (size_t)(og * 16 + lq) * 128 + k * 32 + h * 8;
      s16x8 aH = *(const s16x8*)&WHi[wi];
      s16x8 aL = *(const s16x8*)&WLo[wi];
      acc[ot] = __builtin_amdgcn_mfma_f32_16x16x32_bf16(aH, bH[k], acc[ot], 0, 0, 0);
      acc[ot] = __builtin_amdgcn_mfma_f32_16x16x32_bf16(aH, bL[k], acc[ot], 0, 0, 0);
      acc[ot] = __builtin_amdgcn_mfma_f32_16x16x32_bf16(aL, bH[k], acc[ot], 0, 0, 0);
    }
  }

  size_t cb = (size_t)b * 128 * HW;
  #pragma unroll
  for (int ot = 0; ot < 4; ++ot) {
    int og = oh * 4 + ot;
    float4 bv = *(const float4*)&bias[og * 16 + h * 4];
    #pragma unroll
    for (int i = 0; i < 4; ++i)
      Outf[cb + (size_t)(og * 16 + h * 4 + i) * HW + p] = acc[ot][i] + bv[i];
  }
}

// ---------------------------------------------------------------------------
// Offset branch (unchanged).
// ---------------------------------------------------------------------------
__global__ __launch_bounds__(256) void offset_kernel(
    const float* __restrict__ q, const float* __restrict__ dw_w,
    const float* __restrict__ dw_b, const float* __restrict__ ln_g,
    const float* __restrict__ ln_b, const float* __restrict__ off_w,
    float* __restrict__ pos) {
  __shared__ float vs[64][65];
  __shared__ float mu_s[64], rs_s[64];
  __shared__ float part[4][64][2];
  int bg = blockIdx.x, h = blockIdx.y;
  int t = threadIdx.x;
  int w = t & 63;
  int cq = t >> 6;
  int b = bg >> 1, g = bg & 1;
  const float* qb = q + ((size_t)b * 128 + (size_t)g * 64) * HW;

  #pragma unroll
  for (int i = 0; i < 16; ++i) {
    int c = cq * 16 + i;
    float acc = dw_b[c];
    const float* qc = qb + (size_t)c * HW;
    const float* wc = dw_w + c * 49;
    #pragma unroll
    for (int ky = 0; ky < 7; ++ky) {
      int y = h + ky - 3;
      if (y >= 0 && y < 56) {
        #pragma unroll
        for (int kx = 0; kx < 7; ++kx) {
          int xx = w + kx - 3;
          if (xx >= 0 && xx < 56)
            acc += qc[y * 56 + xx] * wc[ky * 7 + kx];
        }
      }
    }
    vs[c][w] = acc;
  }
  __syncthreads();

  if (cq == 0) {
    float sum = 0.f;
    #pragma unroll 8
    for (int c = 0; c < 64; ++c) sum += vs[c][w];
    float mu = sum * 0.015625f;
    float var = 0.f;
    #pragma unroll 8
    for (int c = 0; c < 64; ++c) { float d = vs[c][w] - mu; var += d * d; }
    mu_s[w] = mu;
    rs_s[w] = rsqrtf(var * 0.015625f + 1e-5f);
  }
  __syncthreads();

  {
    float mu = mu_s[w], rstd = rs_s[w];
    float oy = 0.f, ox = 0.f;
    #pragma unroll
    for (int i = 0; i < 16; ++i) {
      int c = cq * 16 + i;
      float hn = (vs[c][w] - mu) * rstd * ln_g[c] + ln_b[c];
      hn = 0.5f * hn * (1.f + erff(hn * 0.70710678118654752f));
      oy += off_w[c] * hn;
      ox += off_w[64 + c] * hn;
    }
    part[cq][w][0] = oy;
    part[cq][w][1] = ox;
  }
  __syncthreads();

  if (cq == 0 && w < 56) {
    float oy = part[0][w][0] + part[1][w][0] + part[2][w][0] + part[3][w][0];
    float ox = part[0][w][1] + part[1][w][1] + part[2][w][1] + part[3][w][1];
    float py = tanhf(oy) * (2.0f / 56.f) + ((h + 0.5f) * (2.f / 56.f) - 1.f);
    float px = tanhf(ox) * (2.0f / 56.f) + ((w + 0.5f) * (2.f / 56.f) - 1.f);
    int idx = bg * HW + h * 56 + w;
    pos[idx * 2 + 0] = (px + 1.f) * 0.5f * 55.f;
    pos[idx * 2 + 1] = (py + 1.f) * 0.5f * 55.f;
  }
}

// ---------------------------------------------------------------------------
// Bilinear grid sample -> bf16 [b][p][128] (unchanged).
// ---------------------------------------------------------------------------
__global__ __launch_bounds__(256) void sample_kernel(
    const float* __restrict__ x, const float* __restrict__ pos,
    unsigned short* __restrict__ xsT) {
  int t = threadIdx.x;
  int p = blockIdx.x * 64 + (t & 63);
  int cg = t >> 6;
  int bg = p / HW, pp = p % HW;
  int b = bg >> 1, g = bg & 1;
  float gx = pos[2 * p], gy = pos[2 * p + 1];
  float x0f = floorf(gx), y0f = floorf(gy);
  float wx1 = gx - x0f, wx0 = 1.f - wx1;
  float wy1 = gy - y0f, wy0 = 1.f - wy1;
  int x0 = (int)x0f, y0 = (int)y0f;
  int x1 = x0 + 1, y1 = y0 + 1;
  float vx0 = (x0 >= 0 && x0 < 56) ? 1.f : 0.f;
  float vx1 = (x1 >= 0 && x1 < 56) ? 1.f : 0.f;
  float vy0 = (y0 >= 0 && y0 < 56) ? 1.f : 0.f;
  float vy1 = (y1 >= 0 && y1 < 56) ? 1.f : 0.f;
  int xc0 = min(max(x0, 0), 55), xc1 = min(max(x1, 0), 55);
  int yc0 = min(max(y0, 0), 55), yc1 = min(max(y1, 0), 55);
  float w00 = wx0 * wy0 * vx0 * vy0, w10 = wx1 * wy0 * vx1 * vy0;
  float w01 = wx0 * wy1 * vx0 * vy1, w11 = wx1 * wy1 * vx1 * vy1;
  int i00 = yc0 * 56 + xc0, i10 = yc0 * 56 + xc1;
  int i01 = yc1 * 56 + xc0, i11 = yc1 * 56 + xc1;
  const float* xb = x + ((size_t)b * 128 + (size_t)g * 64 + cg * 16) * HW;
  unsigned short tmp[16];
  #pragma unroll 4
  for (int i = 0; i < 16; ++i) {
    const float* xc = xb + (size_t)i * HW;
    tmp[i] = f2bf(w00 * xc[i00] + w10 * xc[i10] + w01 * xc[i01] + w11 * xc[i11]);
  }
  unsigned short* dst = xsT + ((size_t)b * HW + pp) * 128 + g * 64 + cg * 16;
  *(us8*)&dst[0] = *(us8*)&tmp[0];
  *(us8*)&dst[8] = *(us8*)&tmp[8];
}

// ---------------------------------------------------------------------------
// MFMA flash attention v13: round-10 base (dbuf K, V reg prefetch, lgkm-only
// barrier, raw v_exp) + SOFTWARE-PIPELINED SOFTMAX: iteration body is
//   softmax(t) [from saved st] -> QK(t+1) -> PV(t) -> stage/prefetch -> barrier
// so QK(t+1)'s ds_read+MFMA latency overlaps softmax(t)'s trans-pipe chain
// and the P LDS write->read gap gains a full stage of slack.
// grid (49, 16), block 256 = 4 waves.
// ---------------------------------------------------------------------------
__global__ __launch_bounds__(256) void attn_mfma_kernel(
    const unsigned short* __restrict__ qT, const unsigned short* __restrict__ kT,
    const unsigned short* __restrict__ vbf, unsigned short* __restrict__ aoHi,
    unsigned short* __restrict__ aoLo) {
  __shared__ __align__(16) unsigned short Klds[2][64][40];
  __shared__ __align__(16) unsigned short Plds[4][16][68];
  const int KSTEP = 64 * 40;
  int bh = blockIdx.y;
  int b = bh >> 2, hd = bh & 3;
  int t = threadIdx.x;
  int w = t >> 6, l = t & 63;
  int lq = l & 15, h = l >> 4;
  int q0 = blockIdx.x * 64 + w * 16;
  size_t vbase = (size_t)bh * 32 * HW;

  union S8 { s16x8 v; long long q[2]; unsigned short u[8]; };

  S8 qf;
  qf.v = *(const s16x8*)&qT[((size_t)b * HW + q0 + lq) * 128 + hd * 32 + h * 8];

  int srow = t >> 2, sseg = t & 3;
  const unsigned short* ksrc =
      kT + ((size_t)b * HW + srow) * 128 + hd * 32 + sseg * 8;
  unsigned short* kdst = &Klds[0][srow][sseg * 8];

  const unsigned short* vl = vbf + vbase + (size_t)lq * HW + h * 8;

  f32x4 oacc[2] = {{0.f, 0.f, 0.f, 0.f}, {0.f, 0.f, 0.f, 0.f}};
  float lsum = 0.f;

  // ---- prologue: stage K(0),K(1); kreg=K(2); vreg=V(0); QK(0) ----
  S8 kreg, vreg[4];
  {
    S8 k0, k1;
    k0.v = *(const s16x8*)&ksrc[0];
    k1.v = *(const s16x8*)&ksrc[(size_t)64 * 128];
    *(s16x8*)kdst = k0.v;
    *(s16x8*)(kdst + KSTEP) = k1.v;
  }
  kreg.v = *(const s16x8*)&ksrc[(size_t)128 * 128];
  #pragma unroll
  for (int c = 0; c < 2; ++c)
    #pragma unroll
    for (int n = 0; n < 2; ++n)
      vreg[c * 2 + n].v = *(const s16x8*)&vl[(size_t)(n * 16) * HW + c * 32];
  asm volatile("s_waitcnt lgkmcnt(0)" ::: "memory");
  __builtin_amdgcn_s_barrier();

  f32x4 stS[4];
  #pragma unroll
  for (int tt = 0; tt < 4; ++tt) {
    S8 af;
    af.v = *(const s16x8*)&Klds[0][tt * 16 + lq][h * 8];
    stS[tt] = __builtin_amdgcn_mfma_f32_16x16x32_bf16(
        af.v, qf.v, (f32x4){0.f, 0.f, 0.f, 0.f}, 0, 0, 0);
  }

  for (int tix = 0; tix < 48; ++tix) {
    // ---- 1. softmax(tix) from stS -> Plds ----
    #pragma unroll
    for (int tt = 0; tt < 4; ++tt) {
      float p0, p1, p2, p3;
      asm("v_exp_f32 %0, %1" : "=v"(p0) : "v"(stS[tt][0]));
      asm("v_exp_f32 %0, %1" : "=v"(p1) : "v"(stS[tt][1]));
      asm("v_exp_f32 %0, %1" : "=v"(p2) : "v"(stS[tt][2]));
      asm("v_exp_f32 %0, %1" : "=v"(p3) : "v"(stS[tt][3]));
      lsum += (p0 + p1) + (p2 + p3);
      unsigned int lo, hi;
      asm("v_cvt_pk_bf16_f32 %0, %1, %2" : "=v"(lo) : "v"(p0), "v"(p1));
      asm("v_cvt_pk_bf16_f32 %0, %1, %2" : "=v"(hi) : "v"(p2), "v"(p3));
      unsigned long long pk = (unsigned long long)lo | ((unsigned long long)hi << 32);
      *(unsigned long long*)&Plds[w][lq][tt * 16 + h * 4] = pk;
    }

    // ---- 2. QK(tix+1) from Klds[(tix+1)&1] ----
    f32x4 stN[4];
    {
      const unsigned short* buf = &Klds[(tix + 1) & 1][0][0];
      #pragma unroll
      for (int tt = 0; tt < 4; ++tt) {
        S8 af;
        af.v = *(const s16x8*)&buf[(tt * 16 + lq) * 40 + h * 8];
        stN[tt] = __builtin_amdgcn_mfma_f32_16x16x32_bf16(
            af.v, qf.v, (f32x4){0.f, 0.f, 0.f, 0.f}, 0, 0, 0);
      }
    }

    // ---- 3. PV(tix): read P, MFMA with vreg = V(tix) ----
    #pragma unroll
    for (int c = 0; c < 2; ++c) {
      S8 pf;
      pf.q[0] = *(const long long*)&Plds[w][lq][c * 32 + h * 8];
      pf.q[1] = *(const long long*)&Plds[w][lq][c * 32 + h * 8 + 4];
      #pragma unroll
      for (int n = 0; n < 2; ++n)
        oacc[n] = __builtin_amdgcn_mfma_f32_16x16x32_bf16(
            vreg[c * 2 + n].v, pf.v, oacc[n], 0, 0, 0);
    }

    // ---- 4. stage K(tix+2) -> Klds[tix&1]; issue K(tix+3); V(tix+1) ----
    *(s16x8*)(kdst + (tix & 1) * KSTEP) = kreg.v;
    {
      int kbK = (tix + 3 < 49) ? (tix + 3) * 64 : 3072;
      kreg.v = *(const s16x8*)&ksrc[(size_t)kbK * 128];
      int kbV = (tix + 1) * 64;
      #pragma unroll
      for (int c = 0; c < 2; ++c)
        #pragma unroll
        for (int n = 0; n < 2; ++n)
          vreg[c * 2 + n].v =
              *(const s16x8*)&vl[(size_t)(n * 16) * HW + kbV + c * 32];
    }

    // ---- 5. rotate st; lgkm-only barrier ----
    #pragma unroll
    for (int tt = 0; tt < 4; ++tt) stS[tt] = stN[tt];
    asm volatile("s_waitcnt lgkmcnt(0)" ::: "memory");
    __builtin_amdgcn_s_barrier();
  }

  // ---- tail: softmax(48) + PV(48) ----
  #pragma unroll
  for (int tt = 0; tt < 4; ++tt) {
    float p0, p1, p2, p3;
    asm("v_exp_f32 %0, %1" : "=v"(p0) : "v"(stS[tt][0]));
    asm("v_exp_f32 %0, %1" : "=v"(p1) : "v"(stS[tt][1]));
    asm("v_exp_f32 %0, %1" : "=v"(p2) : "v"(stS[tt][2]));
    asm("v_exp_f32 %0, %1" : "=v"(p3) : "v"(stS[tt][3]));
    lsum += (p0 + p1) + (p2 + p3);
    unsigned int lo, hi;
    asm("v_cvt_pk_bf16_f32 %0, %1, %2" : "=v"(lo) : "v"(p0), "v"(p1));
    asm("v_cvt_pk_bf16_f32 %0, %1, %2" : "=v"(hi) : "v"(p2), "v"(p3));
    unsigned long long pk = (unsigned long long)lo | ((unsigned long long)hi << 32);
    *(unsigned long long*)&Plds[w][lq][tt * 16 + h * 4] = pk;
  }
  #pragma unroll
  for (int c = 0; c < 2; ++c) {
    S8 pf;
    pf.q[0] = *(const long long*)&Plds[w][lq][c * 32 + h * 8];
    pf.q[1] = *(const long long*)&Plds[w][lq][c * 32 + h * 8 + 4];
    #pragma unroll
    for (int n = 0; n < 2; ++n)
      oacc[n] = __builtin_amdgcn_mfma_f32_16x16x32_bf16(
          vreg[c * 2 + n].v, pf.v, oacc[n], 0, 0, 0);
  }

  lsum += __shfl_xor(lsum, 16);
  lsum += __shfl_xor(lsum, 32);
  float inv = 1.f / lsum;
  size_t obase = ((size_t)b * HW + q0 + lq) * 128 + hd * 32;
  #pragma unroll
  for (int n = 0; n < 2; ++n) {
    us4 rh, rl;
    #pragma unroll
    for (int r = 0; r < 4; ++r) {
      float v = oacc[n][r] * inv;
      unsigned short hi = f2bf(v);
      rh[r] = hi;
      rl[r] = f2bf(v - bf2f(hi));
    }
    *(us4*)&aoHi[obase + n * 16 + h * 4] = rh;
    *(us4*)&aoLo[obase + n * 16 + h * 4] = rl;
  }
}

// ---------------------------------------------------------------------------
extern "C" void kernel_launch(void* const* d_in, const int* in_sizes, int n_in,
                              void* d_out, int out_size, void* d_ws, size_t ws_size,
                              hipStream_t stream) {
  const float* x    = (const float*)d_in[0];
  const float* dw_w = (const float*)d_in[1];
  const float* dw_b = (const float*)d_in[2];
  const float* ln_g = (const float*)d_in[3];
  const float* ln_b = (const float*)d_in[4];
  const float* offw = (const float*)d_in[5];
  const float* q_w  = (const float*)d_in[6];
  const float* q_b  = (const float*)d_in[7];
  const float* k_w  = (const float*)d_in[8];
  const float* k_b  = (const float*)d_in[9];
  const float* v_w  = (const float*)d_in[10];
  const float* v_b  = (const float*)d_in[11];
  const float* o_w  = (const float*)d_in[12];
  const float* o_b  = (const float*)d_in[13];

  const size_t NE = 1605632;  // 4*128*3136
  float* ws  = (float*)d_ws;
  float* q   = ws;                   // fp32 q [c][p] (offset branch)
  float* pos = q + NE;               // 50176 floats
  unsigned short* xsT  = (unsigned short*)(pos + 50176);  // sampled bf16 [p][128]
  unsigned short* qbT  = xsT + NE;   // q bf16 [p][128] scaled
  unsigned short* kbT  = qbT + NE;   // k bf16 [p][128]
  unsigned short* vb   = kbT + NE;   // v bf16 [c][p]
  unsigned short* aoHi = vb + NE;    // attn out hi bf16 [p][128]
  unsigned short* aoLo = aoHi + NE;  // attn out lo bf16 [p][128]
  unsigned short* Wq   = aoLo + NE;  // 16384 each
  unsigned short* Wk   = Wq + 16384;
  unsigned short* Wv   = Wk + 16384;
  unsigned short* WoH  = Wv + 16384;
  unsigned short* WoL  = WoH + 16384;
  float* out = (float*)d_out;

  wconv_kernel<<<dim3(64, 4), 256, 0, stream>>>(q_w, k_w, v_w, o_w,
                                                Wq, Wk, Wv, WoH, WoL);
  gemm_q_kernel<<<dim3(98, 8), 128, 0, stream>>>(x, Wq, q_b, q, qbT);
  offset_kernel<<<dim3(8, 56), 256, 0, stream>>>(q, dw_w, dw_b, ln_g, ln_b, offw, pos);
  sample_kernel<<<dim3(392), 256, 0, stream>>>(x, pos, xsT);
  gemm_kv_kernel<<<dim3(98, 8), 128, 0, stream>>>(xsT, Wk, Wv, k_b, v_b, kbT, vb);
  attn_mfma_kernel<<<dim3(49, 16), 256, 0, stream>>>(qbT, kbT, vb, aoHi, aoLo);
  o_gemm_kernel<<<dim3(98, 8), 128, 0, stream>>>(aoHi, aoLo, WoH, WoL, o_b, out);
}